// Round 7
// baseline (342.390 us; speedup 1.0000x reference)
//
#include <hip/hip_runtime.h>
#include <hip/hip_bf16.h>
#include <hip/hip_fp16.h>

#define NPTS 8192
#define NB 4
#define R2C 0.5625f
#define BSC (64.0f/0.5625f)
#define IBSC (0.5625f/64.0f)
#define RPW 2      // rows per work unit (finer: tail granularity + tighter prune)
#define WPB 4      // waves per block
#define NGRP 128   // 64-pt groups per batch
#define BCAP 32
#define NUNITS (NB*NPTS/RPW)   // 16384
#define GPB (NPTS/RPW)         // 4096 units per batch
#define NBLK 2048              // main_k grid

typedef unsigned char u8;
typedef unsigned u32;
typedef unsigned long long u64;

__device__ __forceinline__ float wsum(float v){
#pragma unroll
  for (int o=32;o>0;o>>=1) v += __shfl_xor(v,o,64);
  return v;
}
__device__ __forceinline__ float rfl(float v){
  return __int_as_float(__builtin_amdgcn_readfirstlane(__float_as_int(v)));
}
__device__ __forceinline__ int cellof(float x,float y,float z){
  int ix=min(15,max(0,(int)((x+5.f)*1.6f)));
  int iy=min(15,max(0,(int)((y+5.f)*1.6f)));
  int iz=min(15,max(0,(int)((z+5.f)*1.6f)));
  int sx=(ix&1)|((ix&2)<<2)|((ix&4)<<4)|((ix&8)<<6);
  int sy=(iy&1)|((iy&2)<<2)|((iy&4)<<4)|((iy&8)<<6);
  int sz=(iz&1)|((iz&2)<<2)|((iz&4)<<4)|((iz&8)<<6);
  return (sx<<2)|(sy<<1)|sz;
}

// ---------------- sort pipeline ----------------
__global__ void zero_k(u32* __restrict__ hist, u32* __restrict__ ctr){
  int t=blockIdx.x*256+threadIdx.x;
  if (t<NB*4096) hist[t]=0u;
  if (t==0) ctr[0]=0u;
}
__global__ void hist_k(const float* __restrict__ pc, u32* __restrict__ hist){
  int t=blockIdx.x*256+threadIdx.x;
  if (t>=NB*NPTS) return;
  int b=t>>13;
  float x=pc[3*t],y=pc[3*t+1],z=pc[3*t+2];
  atomicAdd(&hist[(b<<12)|cellof(x,y,z)],1u);
}
__global__ void scan_k(u32* __restrict__ hist){
  __shared__ u32 part[256];
  int b=blockIdx.x,t=threadIdx.x;
  u32* h=hist+(b<<12);
  u32 loc[16]; u32 run=0;
#pragma unroll
  for (int k=0;k<16;k++){ u32 v=h[t*16+k]; loc[k]=run; run+=v; }
  part[t]=run; __syncthreads();
  if (t==0){ u32 a=0; for (int i=0;i<256;i++){ u32 v=part[i]; part[i]=a; a+=v; } }
  __syncthreads();
  u32 base=part[t];
#pragma unroll
  for (int k=0;k<16;k++) h[t*16+k]=base+loc[k];
}
__global__ void scat_k(const float* __restrict__ pc, const float* __restrict__ fl,
                       u32* __restrict__ hist, float* __restrict__ srt){
  int t=blockIdx.x*256+threadIdx.x;
  if (t>=NB*NPTS) return;
  int b=t>>13;
  float x=pc[3*t],y=pc[3*t+1],z=pc[3*t+2];
  int c=cellof(x,y,z);
  u32 pos=atomicAdd(&hist[(b<<12)|c],1u);
  int d=b*NPTS+(int)pos;
  srt[d]=x; srt[32768+d]=y; srt[65536+d]=z;
  srt[98304+d]=fl[3*t]; srt[131072+d]=fl[3*t+1]; srt[163840+d]=fl[3*t+2];
}
__global__ void aabb_k(const float* __restrict__ srt, unsigned short* __restrict__ ab){
  int t=blockIdx.x*256+threadIdx.x;
  int w=t>>6, lane=t&63;            // 512 waves
  int j=(w>>7)*NPTS+(w&127)*64+lane;
  float x=srt[j],y=srt[32768+j],z=srt[65536+j];
  float x0=x,x1=x,y0=y,y1=y,z0=z,z1=z;
#pragma unroll
  for (int o=32;o>0;o>>=1){
    x0=fminf(x0,__shfl_xor(x0,o,64)); x1=fmaxf(x1,__shfl_xor(x1,o,64));
    y0=fminf(y0,__shfl_xor(y0,o,64)); y1=fmaxf(y1,__shfl_xor(y1,o,64));
    z0=fminf(z0,__shfl_xor(z0,o,64)); z1=fmaxf(z1,__shfl_xor(z1,o,64));
  }
  if (lane==0){
    unsigned short* p=ab+w*6;
    p[0]=__half_as_ushort(__float2half_rd(x0));
    p[1]=__half_as_ushort(__float2half_ru(x1));
    p[2]=__half_as_ushort(__float2half_rd(y0));
    p[3]=__half_as_ushort(__float2half_ru(y1));
    p[4]=__half_as_ushort(__float2half_rd(z0));
    p[5]=__half_as_ushort(__float2half_ru(z1));
  }
}

// ---------------- final reduction ----------------
__global__ void finp_k(const float* __restrict__ part, float* __restrict__ out){
  int lane=threadIdx.x;
  double k=0.0,b=0.0,d=0.0;
  for (int i=lane;i<NBLK;i+=64){ k+=part[3*i]; b+=part[3*i+1]; d+=part[3*i+2]; }
#pragma unroll
  for (int o=32;o>0;o>>=1){
    k+=__shfl_xor(k,o,64); b+=__shfl_xor(b,o,64); d+=__shfl_xor(d,o,64);
  }
  if (lane==0){
    double knn=k/(32768.0*32.0), bq=b/(32768.0*64.0), dat=d/98304.0;
    out[0]=(float)(0.75*dat+0.25*(0.5*knn+0.5*bq));
  }
}

// ---------------- main loss kernel: fine units + work stealing, no accum atomics ----------------
// launch_bounds(256,4): 128-VGPR cap ((256,8)'s 64-cap spilled, round 4).
__global__ __launch_bounds__(256,4) void main_k(
  const float* __restrict__ fl, const float* __restrict__ gt,
  const float* __restrict__ srt, const unsigned short* __restrict__ ab,
  float* __restrict__ part, u32* __restrict__ ctr)
{
  __shared__ unsigned short sab[NB][NGRP*6];
  __shared__ u32  hist[WPB][RPW][64];
  __shared__ u64  bkey[WPB][RPW][BCAP];
  __shared__ float bl1[WPB][RPW][BCAP];
  __shared__ u8   glg[WPB][NGRP];
  __shared__ float gls[WPB][NGRP];
  __shared__ u8   lst2[WPB][NGRP];
  __shared__ float wred[WPB][3];

  const int tid=threadIdx.x, lane=tid&63, wv=tid>>6, bid=blockIdx.x;
  const u64 lt=(1ull<<lane)-1ull;

  // stage all batches' group AABBs (waves steal cross-batch)
  { const u32* s=(const u32*)ab;
    u32* d=(u32*)&sab[0][0];
    for (int k=tid;k<NB*NGRP*3;k+=256) d[k]=s[k]; }
  __syncthreads();

  // data loss (grid-stride)
  float dl=0.f;
  for (int e=bid*256+tid; e<NB*NPTS*3; e+=gridDim.x*256) dl+=fabsf(fl[e]-gt[e]);
  dl=wsum(dl);

  float tknn=0.f, tbq=0.f;

  for (;;){
    int u;
    if (lane==0) u=(int)atomicAdd(ctr,1u);
    u=__shfl(u,0,64);
    if (u>=NUNITS) break;

    const int b=u>>12;                 // u / GPB (GPB=4096)
    const int i0=(u&(GPB-1))*RPW;
    const float* xs=srt+b*NPTS;        const float* ys=srt+32768+b*NPTS;
    const float* zs=srt+65536+b*NPTS;  const float* fx=srt+98304+b*NPTS;
    const float* fy=srt+131072+b*NPTS; const float* fz=srt+163840+b*NPTS;

    float rx[RPW],ry[RPW],rz[RPW],rfx[RPW],rfy[RPW],rfz[RPW];
#pragma unroll
    for (int r=0;r<RPW;r++){
      rx[r]=rfl(xs[i0+r]); ry[r]=rfl(ys[i0+r]); rz[r]=rfl(zs[i0+r]);
      rfx[r]=rfl(fx[i0+r]); rfy[r]=rfl(fy[i0+r]); rfz[r]=rfl(fz[i0+r]);
    }
    float wx0=rx[0],wx1=rx[0],wy0=ry[0],wy1=ry[0],wz0=rz[0],wz1=rz[0];
#pragma unroll
    for (int r=1;r<RPW;r++){
      wx0=fminf(wx0,rx[r]); wx1=fmaxf(wx1,rx[r]);
      wy0=fminf(wy0,ry[r]); wy1=fmaxf(wy1,ry[r]);
      wz0=fminf(wz0,rz[r]); wz1=fmaxf(wz1,rz[r]);
    }

    // lane-parallel AABB classify + ballot-compact survivor list (ascending g)
    int nsur;
    {
      float d2h[2];
#pragma unroll
      for (int h=0;h<2;h++){
        const unsigned short* a=&sab[b][(h*64+lane)*6];
        float gx0=__half2float(__ushort_as_half(a[0])), gx1=__half2float(__ushort_as_half(a[1]));
        float gy0=__half2float(__ushort_as_half(a[2])), gy1=__half2float(__ushort_as_half(a[3]));
        float gz0=__half2float(__ushort_as_half(a[4])), gz1=__half2float(__ushort_as_half(a[5]));
        float dxm=fmaxf(0.f,fmaxf(gx0-wx1,wx0-gx1));
        float dym=fmaxf(0.f,fmaxf(gy0-wy1,wy0-gy1));
        float dzm=fmaxf(0.f,fmaxf(gz0-wz1,wz0-gz1));
        d2h[h]=fmaf(dxm,dxm,fmaf(dym,dym,dzm*dzm));
      }
      u64 m0=__ballot(d2h[0]<R2C), m1=__ballot(d2h[1]<R2C);
      int c0=__popcll(m0);
      if (d2h[0]<R2C){ int p=__popcll(m0&lt); glg[wv][p]=(u8)lane; gls[wv][p]=d2h[0]; }
      if (d2h[1]<R2C){ int p=c0+__popcll(m1&lt); glg[wv][p]=(u8)(64+lane); gls[wv][p]=d2h[1]; }
      nsur=c0+__popcll(m1);
    }
#pragma unroll
    for (int r=0;r<RPW;r++) hist[wv][r][lane]=0u;

    // ---- pass 1: histogram + online ball query (prefetched) ----
    int cnt[RPW]; float f1[RPW]; float bqa=0.f;
#pragma unroll
    for (int r=0;r<RPW;r++){ cnt[r]=0; f1[r]=0.f; }
    {
      int g=(int)glg[wv][0];
      int jb=g*64+lane;
      float jx=xs[jb],jy=ys[jb],jz=zs[jb];
#pragma unroll 1
      for (int s=0;s<nsur;s++){
        int sn=min(s+1,nsur-1);
        int gn=(int)glg[wv][sn];
        int jb2=gn*64+lane;
        float nx=xs[jb2],ny=ys[jb2],nz=zs[jb2];
        bool open=false;
#pragma unroll
        for (int r=0;r<RPW;r++) open = open || (cnt[r]<64);
        float jfx=0.f,jfy=0.f,jfz=0.f;
        if (open){ jfx=fx[jb],jfy=fy[jb],jfz=fz[jb]; }
#pragma unroll
        for (int r=0;r<RPW;r++){
          float dx=rx[r]-jx, dy=ry[r]-jy, dz=rz[r]-jz;
          float sq=fmaf(dx,dx,fmaf(dy,dy,dz*dz));
          bool in=sq<R2C;
          if (in){
            int bin=min((int)(sq*BSC),63);
            atomicAdd(&hist[wv][r][bin],1u);   // LDS, wave-private
          }
          if (cnt[r]<64){
            u64 m=__ballot(in);
            if (in){
              int p=cnt[r]+__popcll(m&lt);
              if (p<64){
                float l1=fabsf(jfx-rfx[r])+fabsf(jfy-rfy[r])+fabsf(jfz-rfz[r]);
                bqa+=l1;
                if (p==0) f1[r]=l1;
              }
            }
            cnt[r]+=__popcll(m);
          }
        }
        jx=nx; jy=ny; jz=nz; jb=jb2;
      }
    }

    // ---- per-row KNN boundary bin ----
    int bstar[RPW],rneed[RPW];
#pragma unroll
    for (int r=0;r<RPW;r++){
      u32 hh=hist[wv][r][lane];
      u32 inc=hh;
#pragma unroll
      for (int o=1;o<64;o<<=1){ u32 y=__shfl_up(inc,o,64); if (lane>=o) inc+=y; }
      int M=__shfl((int)inc,63,64);
      if (M<=32){ bstar[r]=64; rneed[r]=0; }
      else{
        u32 exc=inc-hh;
        bool sel=(exc<=32u)&&(inc>32u);
        u64 sm=__ballot(sel);
        int src=__ffsll(sm)-1;
        bstar[r]=src;
        rneed[r]=__shfl(32-(int)exc,src,64);
      }
    }
    int mb=0;
#pragma unroll
    for (int r=0;r<RPW;r++) mb=max(mb,bstar[r]);
    float thr2=fminf(R2C,(float)(mb+1)*IBSC);

    // ---- compact pass-2 list by thr2 ----
    int ns2;
    {
      bool c0=(lane<nsur)&&(gls[wv][lane]<thr2);
      bool c1=(64+lane<nsur)&&(gls[wv][64+lane]<thr2);
      u64 b0=__ballot(c0), b1=__ballot(c1);
      int n0=__popcll(b0);
      if (c0){ int p=__popcll(b0&lt); lst2[wv][p]=glg[wv][lane]; }
      if (c1){ int p=n0+__popcll(b1&lt); lst2[wv][p]=glg[wv][64+lane]; }
      ns2=n0+__popcll(b1);
    }

    // ---- pass 2: keep-accumulate + boundary collect (prefetched) ----
    float knn=0.f; int bcnt[RPW];
#pragma unroll
    for (int r=0;r<RPW;r++) bcnt[r]=0;
    if (ns2>0){
      int g=(int)lst2[wv][0];
      int jb=g*64+lane;
      float jx=xs[jb],jy=ys[jb],jz=zs[jb];
      float jfx=fx[jb],jfy=fy[jb],jfz=fz[jb];
#pragma unroll 1
      for (int s=0;s<ns2;s++){
        int sn=min(s+1,ns2-1);
        int gn=(int)lst2[wv][sn];
        int jb2=gn*64+lane;
        float nx=xs[jb2],ny=ys[jb2],nz=zs[jb2];
        float nfx=fx[jb2],nfy=fy[jb2],nfz=fz[jb2];
#pragma unroll
        for (int r=0;r<RPW;r++){
          float dx=rx[r]-jx, dy=ry[r]-jy, dz=rz[r]-jz;
          float sq=fmaf(dx,dx,fmaf(dy,dy,dz*dz));
          bool in=sq<R2C;
          int bin=min((int)(sq*BSC),63);
          bool keep=in&&(bin<bstar[r]);
          bool isb=in&&(bin==bstar[r]);
          float l1=0.f;
          if (keep||isb)
            l1=fabsf(jfx-rfx[r])+fabsf(jfy-rfy[r])+fabsf(jfz-rfz[r]);
          if (keep) knn+=l1;
          u64 mbm=__ballot(isb);
          if (mbm){
            if (isb){
              int p=bcnt[r]+__popcll(mbm&lt);
              if (p<BCAP){
                bkey[wv][r][p]=((u64)__float_as_uint(sq)<<32)|(u32)jb;
                bl1[wv][r][p]=l1;
              }
            }
            bcnt[r]+=__popcll(mbm);
          }
        }
        jx=nx;jy=ny;jz=nz;jfx=nfx;jfy=nfy;jfz=nfz;jb=jb2;
      }
    }

    // ---- boundary exact select + finalize unit ----
#pragma unroll
    for (int r=0;r<RPW;r++){
      if (rneed[r]>0){
        int L=min(bcnt[r],BCAP);
        u64 mykey=~0ull; float myl1=0.f;
        if (lane<L){ mykey=bkey[wv][r][lane]; myl1=bl1[wv][r][lane]; }
        int rank=0;
        for (int q=0;q<L;q++) rank += (bkey[wv][r][q]<mykey)?1:0;
        if (lane<L && rank<rneed[r]) knn+=myl1;
      }
    }
    knn=wsum(knn);
    float bqt=wsum(bqa);
#pragma unroll
    for (int r=0;r<RPW;r++){
      float ff=wsum(f1[r]);
      bqt+=(float)(64-min(cnt[r],64))*ff;
    }
    tknn+=knn; tbq+=bqt;
  }

  // ---- block-level partials (no global atomics) ----
  if (lane==0){ wred[wv][0]=tknn; wred[wv][1]=tbq; wred[wv][2]=dl; }
  __syncthreads();
  if (tid==0){
    float k=0.f,bb=0.f,dd=0.f;
#pragma unroll
    for (int w2=0;w2<WPB;w2++){ k+=wred[w2][0]; bb+=wred[w2][1]; dd+=wred[w2][2]; }
    part[bid*3]=k; part[bid*3+1]=bb; part[bid*3+2]=dd;
  }
}

// ---------------- fallback (verified round-1 kernel) ----------------
#define TILE 1024
#define FRPB 16
#define FRPW 4
__global__ void init_ws_k(double* ws){ int t=threadIdx.x; if(t<3) ws[t]=0.0; }
__global__ void fin_k(const double* __restrict__ ws, float* __restrict__ out){
  double knn = ws[0] / (32768.0*32.0);
  double bq  = ws[1] / (32768.0*64.0);
  double dat = ws[2] / 98304.0;
  out[0] = (float)(0.75*dat + 0.25*(0.5*knn + 0.5*bq));
}
__global__ __launch_bounds__(256) void fb_loss_k(
  const float* __restrict__ pc, const float* __restrict__ fl,
  const float* __restrict__ gt, double* __restrict__ ws)
{
  __shared__ float sx[TILE],sy[TILE],sz[TILE],sfx[TILE],sfy[TILE],sfz[TILE];
  __shared__ unsigned fhist[FRPB][64];
  __shared__ u64 fbkey[FRPB][64];
  __shared__ float fbl1v[FRPB][64];
  const int tid=threadIdx.x, lane=tid&63, wv=tid>>6, bid=blockIdx.x;
  const u64 lt=(1ull<<lane)-1ull;
  float dl=0.f;
  for (int e=bid*256+tid; e<NB*NPTS*3; e+=gridDim.x*256) dl+=fabsf(fl[e]-gt[e]);
  dl=wsum(dl);
  if (lane==0 && dl!=0.f) atomicAdd(ws+2,(double)dl);
  const int row0=bid*FRPB+wv*FRPW;
  const int b=row0/NPTS, i0=row0-b*NPTS;
  const float* pcb=pc+(size_t)b*NPTS*3;
  const float* flb=fl+(size_t)b*NPTS*3;
  float xi[FRPW],yi[FRPW],zi[FRPW],fxi[FRPW],fyi[FRPW],fzi[FRPW];
  int cnt[FRPW]; float bqa[FRPW], f1[FRPW];
#pragma unroll
  for (int r=0;r<FRPW;r++){
    int i=i0+r;
    xi[r]=pcb[3*i]; yi[r]=pcb[3*i+1]; zi[r]=pcb[3*i+2];
    fxi[r]=flb[3*i]; fyi[r]=flb[3*i+1]; fzi[r]=flb[3*i+2];
    cnt[r]=0; bqa[r]=0.f; f1[r]=0.f;
  }
  { unsigned* hp=&fhist[0][0];
    for (int h=tid; h<FRPB*64; h+=256) hp[h]=0u; }
  for (int t=0;t<NPTS/TILE;t++){
#pragma unroll
    for (int k=0;k<TILE/256;k++){
      int p=k*256+tid, g=t*TILE+p;
      sx[p]=pcb[3*g]; sy[p]=pcb[3*g+1]; sz[p]=pcb[3*g+2];
      sfx[p]=flb[3*g]; sfy[p]=flb[3*g+1]; sfz[p]=flb[3*g+2];
    }
    __syncthreads();
#pragma unroll
    for (int r=0;r<FRPW;r++){
      const int wrow=wv*FRPW+r;
#pragma unroll 4
      for (int it=0;it<TILE/64;it++){
        int jl=it*64+lane;
        float dx=sx[jl]-xi[r],dy=sy[jl]-yi[r],dz=sz[jl]-zi[r];
        float sq=fmaf(dx,dx,fmaf(dy,dy,dz*dz));
        bool in=sq<R2C;
        u64 m=__ballot(in);
        if (in){ int bin=min((int)(sq*BSC),63); atomicAdd(&fhist[wrow][bin],1u); }
        if (cnt[r]<64){
          if (in){
            int p=cnt[r]+__popcll(m&lt);
            if (p<64){
              float l1=fabsf(sfx[jl]-fxi[r])+fabsf(sfy[jl]-fyi[r])+fabsf(sfz[jl]-fzi[r]);
              bqa[r]+=l1;
              if (p==0) f1[r]=l1;
            }
          }
        }
        cnt[r]+=__popcll(m);
      }
    }
    __syncthreads();
  }
  int bstar[FRPW],rneed[FRPW];
#pragma unroll
  for (int r=0;r<FRPW;r++){
    const int wrow=wv*FRPW+r;
    unsigned h=fhist[wrow][lane];
    unsigned inc=h;
#pragma unroll
    for (int o=1;o<64;o<<=1){ unsigned y=__shfl_up(inc,o,64); if (lane>=o) inc+=y; }
    int M=__shfl((int)inc,63,64);
    if (M<=32){ bstar[r]=64; rneed[r]=0; }
    else{
      unsigned exc=inc-h;
      bool sel=(exc<=32u)&&(inc>32u);
      u64 sm=__ballot(sel);
      int src=__ffsll(sm)-1;
      bstar[r]=src;
      rneed[r]=__shfl(32-(int)exc,src,64);
    }
  }
  float knn=0.f; int bcnt[FRPW]={0,0,0,0};
  for (int t=0;t<NPTS/TILE;t++){
#pragma unroll
    for (int k=0;k<TILE/256;k++){
      int p=k*256+tid, g=t*TILE+p;
      sx[p]=pcb[3*g]; sy[p]=pcb[3*g+1]; sz[p]=pcb[3*g+2];
      sfx[p]=flb[3*g]; sfy[p]=flb[3*g+1]; sfz[p]=flb[3*g+2];
    }
    __syncthreads();
#pragma unroll
    for (int r=0;r<FRPW;r++){
      const int wrow=wv*FRPW+r;
#pragma unroll 4
      for (int it=0;it<TILE/64;it++){
        int jl=it*64+lane;
        float dx=sx[jl]-xi[r],dy=sy[jl]-yi[r],dz=sz[jl]-zi[r];
        float sq=fmaf(dx,dx,fmaf(dy,dy,dz*dz));
        bool in=sq<R2C;
        int bin=min((int)(sq*BSC),63);
        bool keep=in&&(bin<bstar[r]);
        bool isb=in&&(bin==bstar[r]);
        float l1=0.f;
        if (keep||isb)
          l1=fabsf(sfx[jl]-fxi[r])+fabsf(sfy[jl]-fyi[r])+fabsf(sfz[jl]-fzi[r]);
        if (keep) knn+=l1;
        u64 mb2=__ballot(isb);
        if (isb){
          int p=bcnt[r]+__popcll(mb2&lt);
          if (p<64){
            fbkey[wrow][p]=((u64)__float_as_uint(sq)<<32)|(unsigned)(t*TILE+jl);
            fbl1v[wrow][p]=l1;
          }
        }
        bcnt[r]+=__popcll(mb2);
      }
    }
    __syncthreads();
  }
#pragma unroll
  for (int r=0;r<FRPW;r++){
    const int wrow=wv*FRPW+r;
    int L=min(bcnt[r],64);
    u64 mykey=~0ull; float myl1=0.f;
    if (lane<L){ mykey=fbkey[wrow][lane]; myl1=fbl1v[wrow][lane]; }
    int rank=0;
    for (int q=0;q<L;q++) rank += (fbkey[wrow][q]<mykey)?1:0;
    if (lane<L && rank<rneed[r]) knn+=myl1;
  }
  knn=wsum(knn);
  float bqt=0.f;
#pragma unroll
  for (int r=0;r<FRPW;r++){
    float s=wsum(bqa[r]);
    float ff=wsum(f1[r]);
    s+=(float)(64-min(cnt[r],64))*ff;
    bqt+=s;
  }
  if (lane==0){
    atomicAdd(ws+0,(double)knn);
    atomicAdd(ws+1,(double)bqt);
  }
}

extern "C" void kernel_launch(void* const* d_in, const int* in_sizes, int n_in,
                              void* d_out, int out_size, void* d_ws, size_t ws_size,
                              hipStream_t stream) {
  (void)in_sizes; (void)n_in; (void)out_size;
  const float* pc = (const float*)d_in[0];   // pc_source
  const float* fl = (const float*)d_in[2];   // pred_flow
  const float* gt = (const float*)d_in[3];   // gt_flow
  float* out = (float*)d_out;
  char* w = (char*)d_ws;
  double* acc = (double*)w;
  u32* ctr = (u32*)(w+64);

  const size_t SORT_OFF = 256;
  const size_t AABB_OFF = SORT_OFF + 6u*NB*NPTS*4u;          // 786688
  const size_t HIST_OFF = AABB_OFF + (size_t)NB*NGRP*6*2u;   // 792832
  const size_t PART_OFF = HIST_OFF + (size_t)NB*4096*4u;     // 858368
  const size_t NEED     = PART_OFF + (size_t)NBLK*3*4u;      // 882944

  if (ws_size < NEED){
    hipLaunchKernelGGL(init_ws_k, dim3(1), dim3(64), 0, stream, acc);
    hipLaunchKernelGGL(fb_loss_k, dim3((NB*NPTS)/FRPB), dim3(256), 0, stream,
                       pc, fl, gt, acc);
    hipLaunchKernelGGL(fin_k, dim3(1), dim3(1), 0, stream, acc, out);
    return;
  }
  float* srt = (float*)(w+SORT_OFF);
  unsigned short* ab = (unsigned short*)(w+AABB_OFF);
  u32* hist = (u32*)(w+HIST_OFF);
  float* part = (float*)(w+PART_OFF);

  hipLaunchKernelGGL(zero_k, dim3(64),  dim3(256), 0, stream, hist, ctr);
  hipLaunchKernelGGL(hist_k, dim3(128), dim3(256), 0, stream, pc, hist);
  hipLaunchKernelGGL(scan_k, dim3(4),   dim3(256), 0, stream, hist);
  hipLaunchKernelGGL(scat_k, dim3(128), dim3(256), 0, stream, pc, fl, hist, srt);
  hipLaunchKernelGGL(aabb_k, dim3(128), dim3(256), 0, stream, srt, ab);
  hipLaunchKernelGGL(main_k, dim3(NBLK), dim3(256), 0, stream,
                     fl, gt, srt, ab, part, ctr);
  hipLaunchKernelGGL(finp_k, dim3(1), dim3(64), 0, stream, part, out);
}

// Round 8
// 142.175 us; speedup vs baseline: 2.4082x; 2.4082x over previous
//
#include <hip/hip_runtime.h>
#include <hip/hip_bf16.h>
#include <hip/hip_fp16.h>

#define NPTS 8192
#define NB 4
#define R2C 0.5625f
#define BSC (64.0f/0.5625f)
#define IBSC (0.5625f/64.0f)
#define RPW 2      // rows per work unit
#define WPB 4      // waves per block
#define NGRP 128   // 64-pt groups per batch
#define BCAP 32
#define NUNITS (NB*NPTS/RPW)   // 16384
#define GPB (NPTS/RPW)         // 4096 units per batch
#define NBLK 2048              // main_k grid
#define NCTR 64                // distributed steal counters
#define UPC (NUNITS/NCTR)      // 256 units per counter
#define CSTRIDE 32             // u32 stride between counters (128 B)

typedef unsigned char u8;
typedef unsigned u32;
typedef unsigned long long u64;

__device__ __forceinline__ float wsum(float v){
#pragma unroll
  for (int o=32;o>0;o>>=1) v += __shfl_xor(v,o,64);
  return v;
}
__device__ __forceinline__ float rfl(float v){
  return __int_as_float(__builtin_amdgcn_readfirstlane(__float_as_int(v)));
}
__device__ __forceinline__ int cellof(float x,float y,float z){
  int ix=min(15,max(0,(int)((x+5.f)*1.6f)));
  int iy=min(15,max(0,(int)((y+5.f)*1.6f)));
  int iz=min(15,max(0,(int)((z+5.f)*1.6f)));
  int sx=(ix&1)|((ix&2)<<2)|((ix&4)<<4)|((ix&8)<<6);
  int sy=(iy&1)|((iy&2)<<2)|((iy&4)<<4)|((iy&8)<<6);
  int sz=(iz&1)|((iz&2)<<2)|((iz&4)<<4)|((iz&8)<<6);
  return (sx<<2)|(sy<<1)|sz;
}

// ---------------- sort pipeline ----------------
__global__ void zero_k(u32* __restrict__ hist, u32* __restrict__ ctr){
  int t=blockIdx.x*256+threadIdx.x;
  if (t<NB*4096) hist[t]=0u;
  if (t<NCTR*CSTRIDE) ctr[t]=0u;
}
__global__ void hist_k(const float* __restrict__ pc, u32* __restrict__ hist){
  int t=blockIdx.x*256+threadIdx.x;
  if (t>=NB*NPTS) return;
  int b=t>>13;
  float x=pc[3*t],y=pc[3*t+1],z=pc[3*t+2];
  atomicAdd(&hist[(b<<12)|cellof(x,y,z)],1u);
}
__global__ void scan_k(u32* __restrict__ hist){
  __shared__ u32 part[256];
  int b=blockIdx.x,t=threadIdx.x;
  u32* h=hist+(b<<12);
  u32 loc[16]; u32 run=0;
#pragma unroll
  for (int k=0;k<16;k++){ u32 v=h[t*16+k]; loc[k]=run; run+=v; }
  part[t]=run; __syncthreads();
  if (t==0){ u32 a=0; for (int i=0;i<256;i++){ u32 v=part[i]; part[i]=a; a+=v; } }
  __syncthreads();
  u32 base=part[t];
#pragma unroll
  for (int k=0;k<16;k++) h[t*16+k]=base+loc[k];
}
__global__ void scat_k(const float* __restrict__ pc, const float* __restrict__ fl,
                       u32* __restrict__ hist, float* __restrict__ srt){
  int t=blockIdx.x*256+threadIdx.x;
  if (t>=NB*NPTS) return;
  int b=t>>13;
  float x=pc[3*t],y=pc[3*t+1],z=pc[3*t+2];
  int c=cellof(x,y,z);
  u32 pos=atomicAdd(&hist[(b<<12)|c],1u);
  int d=b*NPTS+(int)pos;
  srt[d]=x; srt[32768+d]=y; srt[65536+d]=z;
  srt[98304+d]=fl[3*t]; srt[131072+d]=fl[3*t+1]; srt[163840+d]=fl[3*t+2];
}
__global__ void aabb_k(const float* __restrict__ srt, unsigned short* __restrict__ ab){
  int t=blockIdx.x*256+threadIdx.x;
  int w=t>>6, lane=t&63;            // 512 waves
  int j=(w>>7)*NPTS+(w&127)*64+lane;
  float x=srt[j],y=srt[32768+j],z=srt[65536+j];
  float x0=x,x1=x,y0=y,y1=y,z0=z,z1=z;
#pragma unroll
  for (int o=32;o>0;o>>=1){
    x0=fminf(x0,__shfl_xor(x0,o,64)); x1=fmaxf(x1,__shfl_xor(x1,o,64));
    y0=fminf(y0,__shfl_xor(y0,o,64)); y1=fmaxf(y1,__shfl_xor(y1,o,64));
    z0=fminf(z0,__shfl_xor(z0,o,64)); z1=fmaxf(z1,__shfl_xor(z1,o,64));
  }
  if (lane==0){
    unsigned short* p=ab+w*6;
    p[0]=__half_as_ushort(__float2half_rd(x0));
    p[1]=__half_as_ushort(__float2half_ru(x1));
    p[2]=__half_as_ushort(__float2half_rd(y0));
    p[3]=__half_as_ushort(__float2half_ru(y1));
    p[4]=__half_as_ushort(__float2half_rd(z0));
    p[5]=__half_as_ushort(__float2half_ru(z1));
  }
}

// ---------------- final reduction ----------------
__global__ void finp_k(const float* __restrict__ part, float* __restrict__ out){
  int lane=threadIdx.x;
  double k=0.0,b=0.0,d=0.0;
  for (int i=lane;i<NBLK;i+=64){ k+=part[3*i]; b+=part[3*i+1]; d+=part[3*i+2]; }
#pragma unroll
  for (int o=32;o>0;o>>=1){
    k+=__shfl_xor(k,o,64); b+=__shfl_xor(b,o,64); d+=__shfl_xor(d,o,64);
  }
  if (lane==0){
    double knn=k/(32768.0*32.0), bq=b/(32768.0*64.0), dat=d/98304.0;
    out[0]=(float)(0.75*dat+0.25*(0.5*knn+0.5*bq));
  }
}

// ---------------- main loss kernel: distributed-counter stealing ----------------
// 64 counters, 128 B apart. Counter c owns units {c + 64k}. ~384 same-address
// atomics per counter (vs 16K on one address in round 7 -> 160+ us serialized).
__global__ __launch_bounds__(256,4) void main_k(
  const float* __restrict__ fl, const float* __restrict__ gt,
  const float* __restrict__ srt, const unsigned short* __restrict__ ab,
  float* __restrict__ part, u32* __restrict__ ctr)
{
  __shared__ unsigned short sab[NB][NGRP*6];
  __shared__ u32  hist[WPB][RPW][64];
  __shared__ u64  bkey[WPB][RPW][BCAP];
  __shared__ float bl1[WPB][RPW][BCAP];
  __shared__ u8   glg[WPB][NGRP];
  __shared__ float gls[WPB][NGRP];
  __shared__ u8   lst2[WPB][NGRP];
  __shared__ float wred[WPB][3];

  const int tid=threadIdx.x, lane=tid&63, wv=tid>>6, bid=blockIdx.x;
  const u64 lt=(1ull<<lane)-1ull;
  const int cidx=(bid&(NCTR-1))*CSTRIDE;   // this block's counter

  // stage all batches' group AABBs (counter partitions span batches)
  { const u32* s=(const u32*)ab;
    u32* d=(u32*)&sab[0][0];
    for (int k=tid;k<NB*NGRP*3;k+=256) d[k]=s[k]; }
  __syncthreads();

  // data loss (grid-stride)
  float dl=0.f;
  for (int e=bid*256+tid; e<NB*NPTS*3; e+=gridDim.x*256) dl+=fabsf(fl[e]-gt[e]);
  dl=wsum(dl);

  float tknn=0.f, tbq=0.f;

  for (;;){
    int k;
    if (lane==0) k=(int)atomicAdd(&ctr[cidx],1u);
    k=__shfl(k,0,64);
    if (k>=UPC) break;
    const int u=(bid&(NCTR-1))+(k<<6);     // interleaved unit of this partition

    const int b=u>>12;                 // u / GPB (GPB=4096)
    const int i0=(u&(GPB-1))*RPW;
    const float* xs=srt+b*NPTS;        const float* ys=srt+32768+b*NPTS;
    const float* zs=srt+65536+b*NPTS;  const float* fx=srt+98304+b*NPTS;
    const float* fy=srt+131072+b*NPTS; const float* fz=srt+163840+b*NPTS;

    float rx[RPW],ry[RPW],rz[RPW],rfx[RPW],rfy[RPW],rfz[RPW];
#pragma unroll
    for (int r=0;r<RPW;r++){
      rx[r]=rfl(xs[i0+r]); ry[r]=rfl(ys[i0+r]); rz[r]=rfl(zs[i0+r]);
      rfx[r]=rfl(fx[i0+r]); rfy[r]=rfl(fy[i0+r]); rfz[r]=rfl(fz[i0+r]);
    }
    float wx0=rx[0],wx1=rx[0],wy0=ry[0],wy1=ry[0],wz0=rz[0],wz1=rz[0];
#pragma unroll
    for (int r=1;r<RPW;r++){
      wx0=fminf(wx0,rx[r]); wx1=fmaxf(wx1,rx[r]);
      wy0=fminf(wy0,ry[r]); wy1=fmaxf(wy1,ry[r]);
      wz0=fminf(wz0,rz[r]); wz1=fmaxf(wz1,rz[r]);
    }

    // lane-parallel AABB classify + ballot-compact survivor list (ascending g)
    int nsur;
    {
      float d2h[2];
#pragma unroll
      for (int h=0;h<2;h++){
        const unsigned short* a=&sab[b][(h*64+lane)*6];
        float gx0=__half2float(__ushort_as_half(a[0])), gx1=__half2float(__ushort_as_half(a[1]));
        float gy0=__half2float(__ushort_as_half(a[2])), gy1=__half2float(__ushort_as_half(a[3]));
        float gz0=__half2float(__ushort_as_half(a[4])), gz1=__half2float(__ushort_as_half(a[5]));
        float dxm=fmaxf(0.f,fmaxf(gx0-wx1,wx0-gx1));
        float dym=fmaxf(0.f,fmaxf(gy0-wy1,wy0-gy1));
        float dzm=fmaxf(0.f,fmaxf(gz0-wz1,wz0-gz1));
        d2h[h]=fmaf(dxm,dxm,fmaf(dym,dym,dzm*dzm));
      }
      u64 m0=__ballot(d2h[0]<R2C), m1=__ballot(d2h[1]<R2C);
      int c0=__popcll(m0);
      if (d2h[0]<R2C){ int p=__popcll(m0&lt); glg[wv][p]=(u8)lane; gls[wv][p]=d2h[0]; }
      if (d2h[1]<R2C){ int p=c0+__popcll(m1&lt); glg[wv][p]=(u8)(64+lane); gls[wv][p]=d2h[1]; }
      nsur=c0+__popcll(m1);
    }
#pragma unroll
    for (int r=0;r<RPW;r++) hist[wv][r][lane]=0u;

    // ---- pass 1: histogram + online ball query (prefetched) ----
    int cnt[RPW]; float f1[RPW]; float bqa=0.f;
#pragma unroll
    for (int r=0;r<RPW;r++){ cnt[r]=0; f1[r]=0.f; }
    {
      int g=(int)glg[wv][0];
      int jb=g*64+lane;
      float jx=xs[jb],jy=ys[jb],jz=zs[jb];
#pragma unroll 1
      for (int s=0;s<nsur;s++){
        int sn=min(s+1,nsur-1);
        int gn=(int)glg[wv][sn];
        int jb2=gn*64+lane;
        float nx=xs[jb2],ny=ys[jb2],nz=zs[jb2];
        bool open=false;
#pragma unroll
        for (int r=0;r<RPW;r++) open = open || (cnt[r]<64);
        float jfx=0.f,jfy=0.f,jfz=0.f;
        if (open){ jfx=fx[jb],jfy=fy[jb],jfz=fz[jb]; }
#pragma unroll
        for (int r=0;r<RPW;r++){
          float dx=rx[r]-jx, dy=ry[r]-jy, dz=rz[r]-jz;
          float sq=fmaf(dx,dx,fmaf(dy,dy,dz*dz));
          bool in=sq<R2C;
          if (in){
            int bin=min((int)(sq*BSC),63);
            atomicAdd(&hist[wv][r][bin],1u);   // LDS, wave-private
          }
          if (cnt[r]<64){
            u64 m=__ballot(in);
            if (in){
              int p=cnt[r]+__popcll(m&lt);
              if (p<64){
                float l1=fabsf(jfx-rfx[r])+fabsf(jfy-rfy[r])+fabsf(jfz-rfz[r]);
                bqa+=l1;
                if (p==0) f1[r]=l1;
              }
            }
            cnt[r]+=__popcll(m);
          }
        }
        jx=nx; jy=ny; jz=nz; jb=jb2;
      }
    }

    // ---- per-row KNN boundary bin ----
    int bstar[RPW],rneed[RPW];
#pragma unroll
    for (int r=0;r<RPW;r++){
      u32 hh=hist[wv][r][lane];
      u32 inc=hh;
#pragma unroll
      for (int o=1;o<64;o<<=1){ u32 y=__shfl_up(inc,o,64); if (lane>=o) inc+=y; }
      int M=__shfl((int)inc,63,64);
      if (M<=32){ bstar[r]=64; rneed[r]=0; }
      else{
        u32 exc=inc-hh;
        bool sel=(exc<=32u)&&(inc>32u);
        u64 sm=__ballot(sel);
        int src=__ffsll(sm)-1;
        bstar[r]=src;
        rneed[r]=__shfl(32-(int)exc,src,64);
      }
    }
    int mb=0;
#pragma unroll
    for (int r=0;r<RPW;r++) mb=max(mb,bstar[r]);
    float thr2=fminf(R2C,(float)(mb+1)*IBSC);

    // ---- compact pass-2 list by thr2 ----
    int ns2;
    {
      bool c0=(lane<nsur)&&(gls[wv][lane]<thr2);
      bool c1=(64+lane<nsur)&&(gls[wv][64+lane]<thr2);
      u64 b0=__ballot(c0), b1=__ballot(c1);
      int n0=__popcll(b0);
      if (c0){ int p=__popcll(b0&lt); lst2[wv][p]=glg[wv][lane]; }
      if (c1){ int p=n0+__popcll(b1&lt); lst2[wv][p]=glg[wv][64+lane]; }
      ns2=n0+__popcll(b1);
    }

    // ---- pass 2: keep-accumulate + boundary collect (prefetched) ----
    float knn=0.f; int bcnt[RPW];
#pragma unroll
    for (int r=0;r<RPW;r++) bcnt[r]=0;
    if (ns2>0){
      int g=(int)lst2[wv][0];
      int jb=g*64+lane;
      float jx=xs[jb],jy=ys[jb],jz=zs[jb];
      float jfx=fx[jb],jfy=fy[jb],jfz=fz[jb];
#pragma unroll 1
      for (int s=0;s<ns2;s++){
        int sn=min(s+1,ns2-1);
        int gn=(int)lst2[wv][sn];
        int jb2=gn*64+lane;
        float nx=xs[jb2],ny=ys[jb2],nz=zs[jb2];
        float nfx=fx[jb2],nfy=fy[jb2],nfz=fz[jb2];
#pragma unroll
        for (int r=0;r<RPW;r++){
          float dx=rx[r]-jx, dy=ry[r]-jy, dz=rz[r]-jz;
          float sq=fmaf(dx,dx,fmaf(dy,dy,dz*dz));
          bool in=sq<R2C;
          int bin=min((int)(sq*BSC),63);
          bool keep=in&&(bin<bstar[r]);
          bool isb=in&&(bin==bstar[r]);
          float l1=0.f;
          if (keep||isb)
            l1=fabsf(jfx-rfx[r])+fabsf(jfy-rfy[r])+fabsf(jfz-rfz[r]);
          if (keep) knn+=l1;
          u64 mbm=__ballot(isb);
          if (mbm){
            if (isb){
              int p=bcnt[r]+__popcll(mbm&lt);
              if (p<BCAP){
                bkey[wv][r][p]=((u64)__float_as_uint(sq)<<32)|(u32)jb;
                bl1[wv][r][p]=l1;
              }
            }
            bcnt[r]+=__popcll(mbm);
          }
        }
        jx=nx;jy=ny;jz=nz;jfx=nfx;jfy=nfy;jfz=nfz;jb=jb2;
      }
    }

    // ---- boundary exact select + finalize unit ----
#pragma unroll
    for (int r=0;r<RPW;r++){
      if (rneed[r]>0){
        int L=min(bcnt[r],BCAP);
        u64 mykey=~0ull; float myl1=0.f;
        if (lane<L){ mykey=bkey[wv][r][lane]; myl1=bl1[wv][r][lane]; }
        int rank=0;
        for (int q=0;q<L;q++) rank += (bkey[wv][r][q]<mykey)?1:0;
        if (lane<L && rank<rneed[r]) knn+=myl1;
      }
    }
    knn=wsum(knn);
    float bqt=wsum(bqa);
#pragma unroll
    for (int r=0;r<RPW;r++){
      float ff=wsum(f1[r]);
      bqt+=(float)(64-min(cnt[r],64))*ff;
    }
    tknn+=knn; tbq+=bqt;
  }

  // ---- block-level partials (no global accumulation atomics) ----
  if (lane==0){ wred[wv][0]=tknn; wred[wv][1]=tbq; wred[wv][2]=dl; }
  __syncthreads();
  if (tid==0){
    float k=0.f,bb=0.f,dd=0.f;
#pragma unroll
    for (int w2=0;w2<WPB;w2++){ k+=wred[w2][0]; bb+=wred[w2][1]; dd+=wred[w2][2]; }
    part[bid*3]=k; part[bid*3+1]=bb; part[bid*3+2]=dd;
  }
}

// ---------------- fallback (verified round-1 kernel) ----------------
#define TILE 1024
#define FRPB 16
#define FRPW 4
__global__ void init_ws_k(double* ws){ int t=threadIdx.x; if(t<3) ws[t]=0.0; }
__global__ void fin_k(const double* __restrict__ ws, float* __restrict__ out){
  double knn = ws[0] / (32768.0*32.0);
  double bq  = ws[1] / (32768.0*64.0);
  double dat = ws[2] / 98304.0;
  out[0] = (float)(0.75*dat + 0.25*(0.5*knn + 0.5*bq));
}
__global__ __launch_bounds__(256) void fb_loss_k(
  const float* __restrict__ pc, const float* __restrict__ fl,
  const float* __restrict__ gt, double* __restrict__ ws)
{
  __shared__ float sx[TILE],sy[TILE],sz[TILE],sfx[TILE],sfy[TILE],sfz[TILE];
  __shared__ unsigned fhist[FRPB][64];
  __shared__ u64 fbkey[FRPB][64];
  __shared__ float fbl1v[FRPB][64];
  const int tid=threadIdx.x, lane=tid&63, wv=tid>>6, bid=blockIdx.x;
  const u64 lt=(1ull<<lane)-1ull;
  float dl=0.f;
  for (int e=bid*256+tid; e<NB*NPTS*3; e+=gridDim.x*256) dl+=fabsf(fl[e]-gt[e]);
  dl=wsum(dl);
  if (lane==0 && dl!=0.f) atomicAdd(ws+2,(double)dl);
  const int row0=bid*FRPB+wv*FRPW;
  const int b=row0/NPTS, i0=row0-b*NPTS;
  const float* pcb=pc+(size_t)b*NPTS*3;
  const float* flb=fl+(size_t)b*NPTS*3;
  float xi[FRPW],yi[FRPW],zi[FRPW],fxi[FRPW],fyi[FRPW],fzi[FRPW];
  int cnt[FRPW]; float bqa[FRPW], f1[FRPW];
#pragma unroll
  for (int r=0;r<FRPW;r++){
    int i=i0+r;
    xi[r]=pcb[3*i]; yi[r]=pcb[3*i+1]; zi[r]=pcb[3*i+2];
    fxi[r]=flb[3*i]; fyi[r]=flb[3*i+1]; fzi[r]=flb[3*i+2];
    cnt[r]=0; bqa[r]=0.f; f1[r]=0.f;
  }
  { unsigned* hp=&fhist[0][0];
    for (int h=tid; h<FRPB*64; h+=256) hp[h]=0u; }
  for (int t=0;t<NPTS/TILE;t++){
#pragma unroll
    for (int k=0;k<TILE/256;k++){
      int p=k*256+tid, g=t*TILE+p;
      sx[p]=pcb[3*g]; sy[p]=pcb[3*g+1]; sz[p]=pcb[3*g+2];
      sfx[p]=flb[3*g]; sfy[p]=flb[3*g+1]; sfz[p]=flb[3*g+2];
    }
    __syncthreads();
#pragma unroll
    for (int r=0;r<FRPW;r++){
      const int wrow=wv*FRPW+r;
#pragma unroll 4
      for (int it=0;it<TILE/64;it++){
        int jl=it*64+lane;
        float dx=sx[jl]-xi[r],dy=sy[jl]-yi[r],dz=sz[jl]-zi[r];
        float sq=fmaf(dx,dx,fmaf(dy,dy,dz*dz));
        bool in=sq<R2C;
        u64 m=__ballot(in);
        if (in){ int bin=min((int)(sq*BSC),63); atomicAdd(&fhist[wrow][bin],1u); }
        if (cnt[r]<64){
          if (in){
            int p=cnt[r]+__popcll(m&lt);
            if (p<64){
              float l1=fabsf(sfx[jl]-fxi[r])+fabsf(sfy[jl]-fyi[r])+fabsf(sfz[jl]-fzi[r]);
              bqa[r]+=l1;
              if (p==0) f1[r]=l1;
            }
          }
        }
        cnt[r]+=__popcll(m);
      }
    }
    __syncthreads();
  }
  int bstar[FRPW],rneed[FRPW];
#pragma unroll
  for (int r=0;r<FRPW;r++){
    const int wrow=wv*FRPW+r;
    unsigned h=fhist[wrow][lane];
    unsigned inc=h;
#pragma unroll
    for (int o=1;o<64;o<<=1){ unsigned y=__shfl_up(inc,o,64); if (lane>=o) inc+=y; }
    int M=__shfl((int)inc,63,64);
    if (M<=32){ bstar[r]=64; rneed[r]=0; }
    else{
      unsigned exc=inc-h;
      bool sel=(exc<=32u)&&(inc>32u);
      u64 sm=__ballot(sel);
      int src=__ffsll(sm)-1;
      bstar[r]=src;
      rneed[r]=__shfl(32-(int)exc,src,64);
    }
  }
  float knn=0.f; int bcnt[FRPW]={0,0,0,0};
  for (int t=0;t<NPTS/TILE;t++){
#pragma unroll
    for (int k=0;k<TILE/256;k++){
      int p=k*256+tid, g=t*TILE+p;
      sx[p]=pcb[3*g]; sy[p]=pcb[3*g+1]; sz[p]=pcb[3*g+2];
      sfx[p]=flb[3*g]; sfy[p]=flb[3*g+1]; sfz[p]=flb[3*g+2];
    }
    __syncthreads();
#pragma unroll
    for (int r=0;r<FRPW;r++){
      const int wrow=wv*FRPW+r;
#pragma unroll 4
      for (int it=0;it<TILE/64;it++){
        int jl=it*64+lane;
        float dx=sx[jl]-xi[r],dy=sy[jl]-yi[r],dz=sz[jl]-zi[r];
        float sq=fmaf(dx,dx,fmaf(dy,dy,dz*dz));
        bool in=sq<R2C;
        int bin=min((int)(sq*BSC),63);
        bool keep=in&&(bin<bstar[r]);
        bool isb=in&&(bin==bstar[r]);
        float l1=0.f;
        if (keep||isb)
          l1=fabsf(sfx[jl]-fxi[r])+fabsf(sfy[jl]-fyi[r])+fabsf(sfz[jl]-fzi[r]);
        if (keep) knn+=l1;
        u64 mb2=__ballot(isb);
        if (isb){
          int p=bcnt[r]+__popcll(mb2&lt);
          if (p<64){
            fbkey[wrow][p]=((u64)__float_as_uint(sq)<<32)|(unsigned)(t*TILE+jl);
            fbl1v[wrow][p]=l1;
          }
        }
        bcnt[r]+=__popcll(mb2);
      }
    }
    __syncthreads();
  }
#pragma unroll
  for (int r=0;r<FRPW;r++){
    const int wrow=wv*FRPW+r;
    int L=min(bcnt[r],64);
    u64 mykey=~0ull; float myl1=0.f;
    if (lane<L){ mykey=fbkey[wrow][lane]; myl1=fbl1v[wrow][lane]; }
    int rank=0;
    for (int q=0;q<L;q++) rank += (fbkey[wrow][q]<mykey)?1:0;
    if (lane<L && rank<rneed[r]) knn+=myl1;
  }
  knn=wsum(knn);
  float bqt=0.f;
#pragma unroll
  for (int r=0;r<FRPW;r++){
    float s=wsum(bqa[r]);
    float ff=wsum(f1[r]);
    s+=(float)(64-min(cnt[r],64))*ff;
    bqt+=s;
  }
  if (lane==0){
    atomicAdd(ws+0,(double)knn);
    atomicAdd(ws+1,(double)bqt);
  }
}

extern "C" void kernel_launch(void* const* d_in, const int* in_sizes, int n_in,
                              void* d_out, int out_size, void* d_ws, size_t ws_size,
                              hipStream_t stream) {
  (void)in_sizes; (void)n_in; (void)out_size;
  const float* pc = (const float*)d_in[0];   // pc_source
  const float* fl = (const float*)d_in[2];   // pred_flow
  const float* gt = (const float*)d_in[3];   // gt_flow
  float* out = (float*)d_out;
  char* w = (char*)d_ws;
  double* acc = (double*)w;

  const size_t SORT_OFF = 256;
  const size_t AABB_OFF = SORT_OFF + 6u*NB*NPTS*4u;          // 786688
  const size_t HIST_OFF = AABB_OFF + (size_t)NB*NGRP*6*2u;   // 792832
  const size_t PART_OFF = HIST_OFF + (size_t)NB*4096*4u;     // 858368
  const size_t CTR_OFF  = PART_OFF + (size_t)NBLK*3*4u;      // 882944
  const size_t NEED     = CTR_OFF + (size_t)NCTR*CSTRIDE*4u; // 891136

  if (ws_size < NEED){
    hipLaunchKernelGGL(init_ws_k, dim3(1), dim3(64), 0, stream, acc);
    hipLaunchKernelGGL(fb_loss_k, dim3((NB*NPTS)/FRPB), dim3(256), 0, stream,
                       pc, fl, gt, acc);
    hipLaunchKernelGGL(fin_k, dim3(1), dim3(1), 0, stream, acc, out);
    return;
  }
  float* srt = (float*)(w+SORT_OFF);
  unsigned short* ab = (unsigned short*)(w+AABB_OFF);
  u32* hist = (u32*)(w+HIST_OFF);
  float* part = (float*)(w+PART_OFF);
  u32* ctr = (u32*)(w+CTR_OFF);

  hipLaunchKernelGGL(zero_k, dim3(64),  dim3(256), 0, stream, hist, ctr);
  hipLaunchKernelGGL(hist_k, dim3(128), dim3(256), 0, stream, pc, hist);
  hipLaunchKernelGGL(scan_k, dim3(4),   dim3(256), 0, stream, hist);
  hipLaunchKernelGGL(scat_k, dim3(128), dim3(256), 0, stream, pc, fl, hist, srt);
  hipLaunchKernelGGL(aabb_k, dim3(128), dim3(256), 0, stream, srt, ab);
  hipLaunchKernelGGL(main_k, dim3(NBLK), dim3(256), 0, stream,
                     fl, gt, srt, ab, part, ctr);
  hipLaunchKernelGGL(finp_k, dim3(1), dim3(64), 0, stream, part, out);
}